// Round 5
// baseline (137.255 us; speedup 1.0000x reference)
//
#include <hip/hip_runtime.h>

#define B_ 2048
#define N_ 1024
#define M_ 4
#define T_ 64
#define R_ 128
#define C_ 10

typedef _Float16 half2v __attribute__((ext_vector_type(2)));
typedef __fp16 fp16x2 __attribute__((ext_vector_type(2)));
typedef float float16v __attribute__((ext_vector_type(16)));
typedef float float2v __attribute__((ext_vector_type(2)));
typedef int int8v __attribute__((ext_vector_type(8)));
typedef unsigned short ushort_t;
typedef unsigned int uint_t;

#define ALPHA   1.171f
#define WENC    9.368f        /* 8 * ALPHA : folds A-scale 2^-3 and alpha into W codes */
#define UFK     1.0205e-5f    /* 0.25 * ALPHA^-64 : folds B-scale 2^-2 and alpha^-64 */

__device__ __forceinline__ uint_t pk16(float a, float b) {
    fp16x2 h = __builtin_amdgcn_cvt_pkrtz(a, b);
    return __builtin_bit_cast(uint_t, h);
}

__device__ __forceinline__ float2v f2(float a, float b) {
    return (float2v){a, b};
}

// Preprocessing (R16 maps; R21: div16 stores x*0.25 so k_main needs no mul).
// blocks [0,512): feature-map+average -> div16 (f16 pairs, premultiplied).
// blocks [512,592): flat gather w-pack to fp4 (e2m1) A-fragments for
// mfma_scale_32x32x64 fmt=4: dword j, byte q, nibble n <-> i = 64ks+32h+8j+2q+n;
// code = fp4(WENC * w_mid[c,i,m,o]), o = 32wv+(lane&31), h = lane>>5;
// frag = (c*4+wv)*8 + m*2 + ks, entry = wtA[frag*64 + lane] (uint4).
__global__ void k_pre(const float* __restrict__ tensor, const float* __restrict__ w_mid,
                      uint2* __restrict__ div16, uint4* __restrict__ wtA) {
    int tid = threadIdx.x;
    if (blockIdx.x < 512) {
        int gid = blockIdx.x * 256 + tid;            // 0 .. B*T-1
        int t = gid >> 11;
        int b = gid & 2047;
        const float4* tp = (const float4*)(tensor + b * N_ + t * 16);
        float a0 = 0.f, a1 = 0.f, a2 = 0.f, a3 = 0.f;
#pragma unroll
        for (int v = 0; v < 4; ++v) {
            float4 xv = tp[v];
            float xs[4] = {xv.x, xv.y, xv.z, xv.w};
#pragma unroll
            for (int p = 0; p < 4; ++p) {
                float ang = 1.57079632679f * xs[p];
                float s, c;
                __sincosf(ang, &s, &c);
                float c2 = c * c, s2 = s * s;
                a0 += c2 * c; a1 += c2 * s; a2 += c * s2; a3 += s2 * s;
            }
        }
        const float sc = 0.25f;    /* (1/16 average) * (4x fold scale) */
        uint2 o; o.x = pk16(a0 * sc, a1 * sc); o.y = pk16(a2 * sc, a3 * sc);
        div16[gid] = o;
    } else {
        int gid = (blockIdx.x - 512) * 256 + tid;    // 0 .. 20479
        int frag = gid >> 6;                         // 0 .. 319
        int lane = gid & 63;
        int c  = frag >> 5;
        int wv = (frag >> 3) & 3;
        int m  = (frag >> 1) & 3;
        int ks = frag & 1;
        int h = lane >> 5, o = wv * 32 + (lane & 31);
        uint_t dw[4];
#pragma unroll
        for (int j = 0; j < 4; ++j) {
            int base = 64 * ks + 32 * h + 8 * j;
            const float* p0 = w_mid + ((c * 128 + base + 0) * 4 + m) * 128 + o;
            const float* p1 = w_mid + ((c * 128 + base + 2) * 4 + m) * 128 + o;
            const float* p2 = w_mid + ((c * 128 + base + 4) * 4 + m) * 128 + o;
            const float* p3 = w_mid + ((c * 128 + base + 6) * 4 + m) * 128 + o;
            uint_t acc = 0;
            acc = __builtin_amdgcn_cvt_scalef32_pk_fp4_f32(acc, p0[0] * WENC, p0[512] * WENC, 1.0f, 0);
            acc = __builtin_amdgcn_cvt_scalef32_pk_fp4_f32(acc, p1[0] * WENC, p1[512] * WENC, 1.0f, 1);
            acc = __builtin_amdgcn_cvt_scalef32_pk_fp4_f32(acc, p2[0] * WENC, p2[512] * WENC, 1.0f, 2);
            acc = __builtin_amdgcn_cvt_scalef32_pk_fp4_f32(acc, p3[0] * WENC, p3[512] * WENC, 1.0f, 3);
            dw[j] = acc;
        }
        wtA[frag * 64 + lane] = make_uint4(dw[0], dw[1], dw[2], dw[3]);
    }
}

// 64-step recurrence, R21/R22 = R20 structure (4 waves, 1 o-tile each,
// double-buffered LDS state, 1 barrier/step, validated maps) + VALU DIET.
// R20 counters: VALUBusy 63% / MfmaUtil 22% — issue port loaded with ~370
// VALU instr/wave/step vs ~150 required (per-step A-operand rebuild, x decode,
// scalar fold).  Diet: (1) persistent zero-padded int8v A-operands,
// (2) premultiplied f16 x (decode = 4 cvt, no mul), (3) fold in float2
// ext-vectors so the compiler emits v_pk_fma_f32 (2 FMA/instr).
__global__ void __launch_bounds__(256)
k_main(const uint2* __restrict__ div16, const uint4* __restrict__ wtA,
       const float* __restrict__ w_first, const float* __restrict__ w_last,
       float* __restrict__ logits) {
    __shared__ __align__(16) char st[2][2048];   // [buf][16 dword-chunks x 32 b x 4 B]

    const int tid = threadIdx.x;
    const int wv = tid >> 6;       // wave id == o-tile index tl
    const int lane = tid & 63;
    const int c  = blockIdx.y;
    const int b0 = blockIdx.x * 32;
    const int h = lane >> 5;       // k-half
    const int b31 = lane & 31;     // b col (B/D) == o col offset (A rows)

    // W A-operands: persistent, pre-padded.  4 m x 2 ks x 8 dwords = 64 VGPRs.
    int8v wa[4][2];
    {
        const uint4* wb = wtA + (c * 4 + wv) * 8 * 64 + lane;
#pragma unroll
        for (int m = 0; m < 4; ++m)
#pragma unroll
            for (int ks = 0; ks < 2; ++ks) {
                uint4 w = wb[(m * 2 + ks) * 64];
                wa[m][ks] = (int8v){(int)w.x, (int)w.y, (int)w.z, (int)w.w, 0, 0, 0, 0};
            }
    }

    // Initial state: s0[i] = sum_m w_first[c,0,m,i]; code = fp4(4*s0), all b.
    // Wave 0 lanes <16 each own dword-chunk q=lane; write 32 b copies to st[0].
    if (wv == 0 && lane < 16) {
        float v[8];
#pragma unroll
        for (int n = 0; n < 8; ++n) {
            float s = 0.f;
#pragma unroll
            for (int m = 0; m < 4; ++m) s += w_first[(c * 4 + m) * 128 + lane * 8 + n];
            v[n] = 4.f * s;
        }
        uint_t pk = 0;
        pk = __builtin_amdgcn_cvt_scalef32_pk_fp4_f32(pk, v[0], v[1], 1.0f, 0);
        pk = __builtin_amdgcn_cvt_scalef32_pk_fp4_f32(pk, v[2], v[3], 1.0f, 1);
        pk = __builtin_amdgcn_cvt_scalef32_pk_fp4_f32(pk, v[4], v[5], 1.0f, 2);
        pk = __builtin_amdgcn_cvt_scalef32_pk_fp4_f32(pk, v[6], v[7], 1.0f, 3);
#pragma unroll
        for (int b = 0; b < 32; ++b)
            *(uint_t*)(st[0] + lane * 128 + b * 4) = pk;
    }

    // T-invariant LDS byte offsets (R16-validated maps).
    int roff[2][4];                // B-operand dwords: chunk 8ks+4h+j
#pragma unroll
    for (int ks = 0; ks < 2; ++ks)
#pragma unroll
        for (int j = 0; j < 4; ++j)
            roff[ks][j] = (8 * ks + 4 * h + j) * 128 + b31 * 4;
    int woff[4];                   // reg-quad rb -> chunk 4*wv+rb, byte 2h
#pragma unroll
    for (int rb = 0; rb < 4; ++rb)
        woff[rb] = (4 * wv + rb) * 128 + b31 * 4 + 2 * h;

    const float16v z16 = (float16v)(0.0f);

    __syncthreads();               // init visible to all waves

    const uint2* xq = div16 + b0 + b31;   // stride B_ per t
    uint2 xd = xq[0];              // t = 0, prefetched
    for (int t = 0; t < T_; ++t) {
        // Prefetch next step's x early (address independent of loop state).
        int tn = (t + 1 < T_) ? t + 1 : t;
        uint2 xd_nx = xq[tn * B_];

        // Decode current x (premultiplied in k_pre; h-pair broadcasts).
        half2v xlo = __builtin_bit_cast(half2v, xd.x);
        half2v xhi = __builtin_bit_cast(half2v, xd.y);
        float x0 = (float)xlo.x, x1 = (float)xlo.y;
        float x2 = (float)xhi.x, x3 = (float)xhi.y;

        const char* cb = st[t & 1];          // state(t)
        char* nbuf = st[(t + 1) & 1];        // state(t+1)

        // State (B operands) — one read batch.
        int8v bv0 = (int8v){ *(const int*)(cb + roff[0][0]), *(const int*)(cb + roff[0][1]),
                             *(const int*)(cb + roff[0][2]), *(const int*)(cb + roff[0][3]), 0, 0, 0, 0 };
        int8v bv1 = (int8v){ *(const int*)(cb + roff[1][0]), *(const int*)(cb + roff[1][1]),
                             *(const int*)(cb + roff[1][2]), *(const int*)(cb + roff[1][3]), 0, 0, 0, 0 };

        float16v am[4];
#pragma unroll
        for (int m = 0; m < 4; ++m) {
            am[m] = __builtin_amdgcn_mfma_scale_f32_32x32x64_f8f6f4(
                wa[m][0], bv0, z16, 4, 4, 0, 124, 0, 125);
            am[m] = __builtin_amdgcn_mfma_scale_f32_32x32x64_f8f6f4(
                wa[m][1], bv1, am[m], 4, 4, 0, 124, 0, 125);
        }
        // Fold + encode (float2 -> v_pk_fma_f32).  D: col=b31,
        // row=(reg&3)+8*(reg>>2)+4h; reg quad rb: rows 8rb+4h+e ->
        // i = 32*wv+8rb+4h+e -> chunk 4*wv+rb, nibble 4h+e.
#pragma unroll
        for (int rb = 0; rb < 4; ++rb) {
            float2v v01 = f2(am[0][4*rb+0], am[0][4*rb+1]) * x0
                        + f2(am[1][4*rb+0], am[1][4*rb+1]) * x1
                        + f2(am[2][4*rb+0], am[2][4*rb+1]) * x2
                        + f2(am[3][4*rb+0], am[3][4*rb+1]) * x3;
            float2v v23 = f2(am[0][4*rb+2], am[0][4*rb+3]) * x0
                        + f2(am[1][4*rb+2], am[1][4*rb+3]) * x1
                        + f2(am[2][4*rb+2], am[2][4*rb+3]) * x2
                        + f2(am[3][4*rb+2], am[3][4*rb+3]) * x3;
            uint_t pk = __builtin_amdgcn_cvt_scalef32_pk_fp4_f32(0u, v01.x, v01.y, 1.0f, 0);
            pk = __builtin_amdgcn_cvt_scalef32_pk_fp4_f32(pk, v23.x, v23.y, 1.0f, 1);
            *(ushort_t*)(nbuf + woff[rb]) = (ushort_t)(pk & 0xFFFFu);
        }
        __syncthreads();           // publish state(t+1); completes this wave's reads of cb
        xd = xd_nx;
    }

    // Final contraction (wave 0): logits[b,c] = sum_i state_true[b,i]*uf[i],
    // state_true = (code/4)*alpha^-64; uf[i] = UFK * sum_m w_last[c,i,m].
    // state(64) sits in st[0] (64 is even).
    if (wv == 0) {
        const float tbl[8] = {0.f, 0.5f, 1.f, 1.5f, 2.f, 3.f, 4.f, 6.f};
        float p = 0.f;
#pragma unroll
        for (int ks = 0; ks < 2; ++ks)
#pragma unroll
            for (int j = 0; j < 4; ++j) {
                uint_t dwv = *(const uint_t*)(st[0] + roff[ks][j]);
#pragma unroll
                for (int nb = 0; nb < 8; ++nb) {
                    int i = 64 * ks + 32 * h + 8 * j + nb;
                    float4 wl4 = *(const float4*)(w_last + (c * 128 + i) * 4);
                    float ufi = UFK * (wl4.x + wl4.y + wl4.z + wl4.w);
                    int nib = (dwv >> (nb * 4)) & 0xF;
                    float mag = tbl[nib & 7];
                    p += (nib & 8 ? -mag : mag) * ufi;
                }
            }
        p += __shfl_xor(p, 32);
        if (h == 0) logits[(b0 + b31) * C_ + c] = p;
    }
}

// Log-softmax over C=10, output FLOAT32.
__global__ void k_lsm(const float* __restrict__ logits, float* __restrict__ out) {
    int b = blockIdx.x * 256 + threadIdx.x;
    float x[C_];
    float mx = -1e30f;
#pragma unroll
    for (int c = 0; c < C_; ++c) { x[c] = logits[b * C_ + c]; mx = fmaxf(mx, x[c]); }
    float s = 0.f;
#pragma unroll
    for (int c = 0; c < C_; ++c) s += __expf(x[c] - mx);
    float lse = mx + __logf(s);
#pragma unroll
    for (int c = 0; c < C_; ++c) out[b * C_ + c] = x[c] - lse;
}

extern "C" void kernel_launch(void* const* d_in, const int* in_sizes, int n_in,
                              void* d_out, int out_size, void* d_ws, size_t ws_size,
                              hipStream_t stream) {
    const float* tensor  = (const float*)d_in[0];   // (B,N)      f32
    const float* w_first = (const float*)d_in[1];   // (C,1,M,R)  f32
    const float* w_mid   = (const float*)d_in[2];   // (C,R,M,R)  f32
    const float* w_last  = (const float*)d_in[3];   // (C,R,M,1)  f32
    char* ws = (char*)d_ws;
    uint2* div16 = (uint2*)ws;                               // 1 MiB
    uint4* wtA   = (uint4*)(ws + 1048576);                   // 320 KB (fp4)
    float* logits = (float*)(ws + 1048576 + 327680);         // 80 KB
    float* out = (float*)d_out;                              // (B,C) f32

    k_pre<<<592, 256, 0, stream>>>(tensor, w_mid, div16, wtA);
    k_main<<<dim3(64, 10), 256, 0, stream>>>(div16, wtA, w_first, w_last, logits);
    k_lsm<<<8, 256, 0, stream>>>(logits, out);
}

// Round 6
// 122.512 us; speedup vs baseline: 1.1203x; 1.1203x over previous
//
#include <hip/hip_runtime.h>

#define B_ 2048
#define N_ 1024
#define M_ 4
#define T_ 64
#define R_ 128
#define C_ 10

typedef _Float16 half2v __attribute__((ext_vector_type(2)));
typedef __fp16 fp16x2 __attribute__((ext_vector_type(2)));
typedef float float16v __attribute__((ext_vector_type(16)));
typedef float float2v __attribute__((ext_vector_type(2)));
typedef int int8v __attribute__((ext_vector_type(8)));
typedef unsigned short ushort_t;
typedef unsigned int uint_t;

#define ALPHA   1.171f
#define WENC    9.368f        /* 8 * ALPHA : folds A-scale 2^-3 and alpha into W codes */
#define UFK     1.0205e-5f    /* 0.25 * ALPHA^-64 : folds B-scale 2^-2 and alpha^-64 */

__device__ __forceinline__ uint_t pk16(float a, float b) {
    fp16x2 h = __builtin_amdgcn_cvt_pkrtz(a, b);
    return __builtin_bit_cast(uint_t, h);
}

__device__ __forceinline__ float2v f2(float a, float b) {
    return (float2v){a, b};
}

// Preprocessing (R16 maps; div16 stores x*0.25 so k_main needs no mul).
// blocks [0,512): feature-map+average -> div16 (f16 pairs, premultiplied).
// blocks [512,592): flat gather w-pack to fp4 (e2m1) A-fragments for
// mfma_scale_32x32x64 fmt=4: dword j, byte q, nibble n <-> i = 64ks+32h+8j+2q+n;
// code = fp4(WENC * w_mid[c,i,m,o]), o = 32wv+(lane&31), h = lane>>5;
// frag = (c*4+wv)*8 + m*2 + ks, entry = wtA[frag*64 + lane] (uint4).
__global__ void k_pre(const float* __restrict__ tensor, const float* __restrict__ w_mid,
                      uint2* __restrict__ div16, uint4* __restrict__ wtA) {
    int tid = threadIdx.x;
    if (blockIdx.x < 512) {
        int gid = blockIdx.x * 256 + tid;            // 0 .. B*T-1
        int t = gid >> 11;
        int b = gid & 2047;
        const float4* tp = (const float4*)(tensor + b * N_ + t * 16);
        float a0 = 0.f, a1 = 0.f, a2 = 0.f, a3 = 0.f;
#pragma unroll
        for (int v = 0; v < 4; ++v) {
            float4 xv = tp[v];
            float xs[4] = {xv.x, xv.y, xv.z, xv.w};
#pragma unroll
            for (int p = 0; p < 4; ++p) {
                float ang = 1.57079632679f * xs[p];
                float s, c;
                __sincosf(ang, &s, &c);
                float c2 = c * c, s2 = s * s;
                a0 += c2 * c; a1 += c2 * s; a2 += c * s2; a3 += s2 * s;
            }
        }
        const float sc = 0.25f;    /* (1/16 average) * (4x fold scale) */
        uint2 o; o.x = pk16(a0 * sc, a1 * sc); o.y = pk16(a2 * sc, a3 * sc);
        div16[gid] = o;
    } else {
        int gid = (blockIdx.x - 512) * 256 + tid;    // 0 .. 20479
        int frag = gid >> 6;                         // 0 .. 319
        int lane = gid & 63;
        int c  = frag >> 5;
        int wv = (frag >> 3) & 3;
        int m  = (frag >> 1) & 3;
        int ks = frag & 1;
        int h = lane >> 5, o = wv * 32 + (lane & 31);
        uint_t dw[4];
#pragma unroll
        for (int j = 0; j < 4; ++j) {
            int base = 64 * ks + 32 * h + 8 * j;
            const float* p0 = w_mid + ((c * 128 + base + 0) * 4 + m) * 128 + o;
            const float* p1 = w_mid + ((c * 128 + base + 2) * 4 + m) * 128 + o;
            const float* p2 = w_mid + ((c * 128 + base + 4) * 4 + m) * 128 + o;
            const float* p3 = w_mid + ((c * 128 + base + 6) * 4 + m) * 128 + o;
            uint_t acc = 0;
            acc = __builtin_amdgcn_cvt_scalef32_pk_fp4_f32(acc, p0[0] * WENC, p0[512] * WENC, 1.0f, 0);
            acc = __builtin_amdgcn_cvt_scalef32_pk_fp4_f32(acc, p1[0] * WENC, p1[512] * WENC, 1.0f, 1);
            acc = __builtin_amdgcn_cvt_scalef32_pk_fp4_f32(acc, p2[0] * WENC, p2[512] * WENC, 1.0f, 2);
            acc = __builtin_amdgcn_cvt_scalef32_pk_fp4_f32(acc, p3[0] * WENC, p3[512] * WENC, 1.0f, 3);
            dw[j] = acc;
        }
        wtA[frag * 64 + lane] = make_uint4(dw[0], dw[1], dw[2], dw[3]);
    }
}

// 64-step recurrence, R22 = R20/R21 structure (4 waves, 1 o-tile each,
// double-buffered LDS state, 1 barrier/step, validated maps) + REGISTER FIX.
// R21 evidence: VGPR_Count=84 — too small for the working set; compiler parked
// wa/am in AGPRs with v_accvgpr shuttles (~64-128 hidden VALU instr/step),
// explaining measured ~305 VALU/wave/step vs ~150 hand-count, and why the
// diet (VALUBusy 63->51) didn't shorten the step on issue-saturated pacer CUs.
// Fix: (1) __launch_bounds__(256,3) raises VGPR cap to ~170 (only 3 waves/SIMD
// needed: 640 blocks -> max 3 blocks/CU); (2) incremental fold keeps ONE am
// accumulator live; (3) t-loop unrolled by 2 with static per-buffer LDS
// immediates (no buffer-select, no address VALU per step).
__global__ void __launch_bounds__(256, 3)
k_main(const uint2* __restrict__ div16, const uint4* __restrict__ wtA,
       const float* __restrict__ w_first, const float* __restrict__ w_last,
       float* __restrict__ logits) {
    __shared__ __align__(16) char st[2][2048];   // [buf][16 dword-chunks x 32 b x 4 B]

    const int tid = threadIdx.x;
    const int wv = tid >> 6;       // wave id == o-tile index tl
    const int lane = tid & 63;
    const int c  = blockIdx.y;
    const int b0 = blockIdx.x * 32;
    const int h = lane >> 5;       // k-half
    const int b31 = lane & 31;     // b col (B/D) == o col offset (A rows)

    // W A-operands: persistent, pre-padded.  4 m x 2 ks x 8 dwords = 64 regs.
    int8v wa[4][2];
    {
        const uint4* wb = wtA + (c * 4 + wv) * 8 * 64 + lane;
#pragma unroll
        for (int m = 0; m < 4; ++m)
#pragma unroll
            for (int ks = 0; ks < 2; ++ks) {
                uint4 w = wb[(m * 2 + ks) * 64];
                wa[m][ks] = (int8v){(int)w.x, (int)w.y, (int)w.z, (int)w.w, 0, 0, 0, 0};
            }
    }

    // Initial state: s0[i] = sum_m w_first[c,0,m,i]; code = fp4(4*s0), all b.
    // Wave 0 lanes <16 each own dword-chunk q=lane; write 32 b copies to st[0].
    if (wv == 0 && lane < 16) {
        float v[8];
#pragma unroll
        for (int n = 0; n < 8; ++n) {
            float s = 0.f;
#pragma unroll
            for (int m = 0; m < 4; ++m) s += w_first[(c * 4 + m) * 128 + lane * 8 + n];
            v[n] = 4.f * s;
        }
        uint_t pk = 0;
        pk = __builtin_amdgcn_cvt_scalef32_pk_fp4_f32(pk, v[0], v[1], 1.0f, 0);
        pk = __builtin_amdgcn_cvt_scalef32_pk_fp4_f32(pk, v[2], v[3], 1.0f, 1);
        pk = __builtin_amdgcn_cvt_scalef32_pk_fp4_f32(pk, v[4], v[5], 1.0f, 2);
        pk = __builtin_amdgcn_cvt_scalef32_pk_fp4_f32(pk, v[6], v[7], 1.0f, 3);
#pragma unroll
        for (int b = 0; b < 32; ++b)
            *(uint_t*)(st[0] + lane * 128 + b * 4) = pk;
    }

    // Static LDS addressing (R16-validated maps, reduced to base+immediate):
    // read  chunk 8ks+4h+j  -> vaddr rbase = b31*4 + h*512, imm ks*1024 + j*128
    // write chunk 4wv+rb    -> vaddr wbase = b31*4 + 2h + wv*512, imm rb*128
    const int rbase = b31 * 4 + h * 512;
    const int wbase = b31 * 4 + 2 * h + wv * 512;
    char* const sbase = &st[0][0];

    const float16v z16 = (float16v)(0.0f);

    __syncthreads();               // init visible to all waves

    // One recurrence substep: read state from buf rb_, write state(t+1) to buf wb_.
    auto step = [&](const char* cb, char* nbuf, uint_t xdx, uint_t xdy) {
        half2v xlo = __builtin_bit_cast(half2v, xdx);
        half2v xhi = __builtin_bit_cast(half2v, xdy);
        float xs0 = (float)xlo.x, xs1 = (float)xlo.y;
        float xs2 = (float)xhi.x, xs3 = (float)xhi.y;

        int8v bv0 = (int8v){ *(const int*)(cb + rbase +    0), *(const int*)(cb + rbase +  128),
                             *(const int*)(cb + rbase +  256), *(const int*)(cb + rbase +  384), 0, 0, 0, 0 };
        int8v bv1 = (int8v){ *(const int*)(cb + rbase + 1024), *(const int*)(cb + rbase + 1152),
                             *(const int*)(cb + rbase + 1280), *(const int*)(cb + rbase + 1408), 0, 0, 0, 0 };

        // Incremental fold: one am live at a time; vA/vB accumulate across m.
        float2v vA[4], vB[4];
#pragma unroll
        for (int m = 0; m < 4; ++m) {
            float16v am = __builtin_amdgcn_mfma_scale_f32_32x32x64_f8f6f4(
                wa[m][0], bv0, z16, 4, 4, 0, 124, 0, 125);
            am = __builtin_amdgcn_mfma_scale_f32_32x32x64_f8f6f4(
                wa[m][1], bv1, am, 4, 4, 0, 124, 0, 125);
            float xm = (m == 0) ? xs0 : (m == 1) ? xs1 : (m == 2) ? xs2 : xs3;
#pragma unroll
            for (int rb = 0; rb < 4; ++rb) {
                float2v lo = f2(am[4*rb+0], am[4*rb+1]);
                float2v hi = f2(am[4*rb+2], am[4*rb+3]);
                if (m == 0) { vA[rb] = lo * xm; vB[rb] = hi * xm; }
                else        { vA[rb] += lo * xm; vB[rb] += hi * xm; }
            }
        }
        // Encode + write.  D: col=b31, row=(reg&3)+8*(reg>>2)+4h; reg quad rb:
        // rows 8rb+4h+e -> i = 32wv+8rb+4h+e -> chunk 4wv+rb, nibble 4h+e.
#pragma unroll
        for (int rb = 0; rb < 4; ++rb) {
            uint_t pk = __builtin_amdgcn_cvt_scalef32_pk_fp4_f32(0u, vA[rb].x, vA[rb].y, 1.0f, 0);
            pk = __builtin_amdgcn_cvt_scalef32_pk_fp4_f32(pk, vB[rb].x, vB[rb].y, 1.0f, 1);
            *(ushort_t*)(nbuf + wbase + rb * 128) = (ushort_t)(pk & 0xFFFFu);
        }
        __syncthreads();           // publish state(t+1); completes reads of cb
    };

    const uint2* xp = div16 + b0 + b31;   // stride B_ per t
    uint2 xd = xp[0];              // x(0), prefetched
    for (int t = 0; t < T_; t += 2) {
        // substep A (even t): st[0] -> st[1]
        uint2 xn = xp[(t + 1) * B_];          // x(t+1), t+1 <= 63
        step(sbase, sbase + 2048, xd.x, xd.y);
        xd = xn;
        // substep B (odd t+1): st[1] -> st[0]
        int tn2 = (t + 2 < T_) ? t + 2 : T_ - 1;   // clamped; value unused on last iter
        uint2 xn2 = xp[tn2 * B_];
        step(sbase + 2048, sbase, xd.x, xd.y);
        xd = xn2;
    }

    // Final contraction (wave 0): logits[b,c] = sum_i state_true[b,i]*uf[i],
    // state_true = (code/4)*alpha^-64; uf[i] = UFK * sum_m w_last[c,i,m].
    // state(64) sits in st[0] (64 is even).
    if (wv == 0) {
        const float tbl[8] = {0.f, 0.5f, 1.f, 1.5f, 2.f, 3.f, 4.f, 6.f};
        float p = 0.f;
#pragma unroll
        for (int ks = 0; ks < 2; ++ks)
#pragma unroll
            for (int j = 0; j < 4; ++j) {
                uint_t dwv = *(const uint_t*)(sbase + rbase + ks * 1024 + j * 128);
#pragma unroll
                for (int nb = 0; nb < 8; ++nb) {
                    int i = 64 * ks + 32 * h + 8 * j + nb;
                    float4 wl4 = *(const float4*)(w_last + (c * 128 + i) * 4);
                    float ufi = UFK * (wl4.x + wl4.y + wl4.z + wl4.w);
                    int nib = (dwv >> (nb * 4)) & 0xF;
                    float mag = tbl[nib & 7];
                    p += (nib & 8 ? -mag : mag) * ufi;
                }
            }
        p += __shfl_xor(p, 32);
        if (h == 0) logits[(b0 + b31) * C_ + c] = p;
    }
}

// Log-softmax over C=10, output FLOAT32.
__global__ void k_lsm(const float* __restrict__ logits, float* __restrict__ out) {
    int b = blockIdx.x * 256 + threadIdx.x;
    float x[C_];
    float mx = -1e30f;
#pragma unroll
    for (int c = 0; c < C_; ++c) { x[c] = logits[b * C_ + c]; mx = fmaxf(mx, x[c]); }
    float s = 0.f;
#pragma unroll
    for (int c = 0; c < C_; ++c) s += __expf(x[c] - mx);
    float lse = mx + __logf(s);
#pragma unroll
    for (int c = 0; c < C_; ++c) out[b * C_ + c] = x[c] - lse;
}

extern "C" void kernel_launch(void* const* d_in, const int* in_sizes, int n_in,
                              void* d_out, int out_size, void* d_ws, size_t ws_size,
                              hipStream_t stream) {
    const float* tensor  = (const float*)d_in[0];   // (B,N)      f32
    const float* w_first = (const float*)d_in[1];   // (C,1,M,R)  f32
    const float* w_mid   = (const float*)d_in[2];   // (C,R,M,R)  f32
    const float* w_last  = (const float*)d_in[3];   // (C,R,M,1)  f32
    char* ws = (char*)d_ws;
    uint2* div16 = (uint2*)ws;                               // 1 MiB
    uint4* wtA   = (uint4*)(ws + 1048576);                   // 320 KB (fp4)
    float* logits = (float*)(ws + 1048576 + 327680);         // 80 KB
    float* out = (float*)d_out;                              // (B,C) f32

    k_pre<<<592, 256, 0, stream>>>(tensor, w_mid, div16, wtA);
    k_main<<<dim3(64, 10), 256, 0, stream>>>(div16, wtA, w_first, w_last, logits);
    k_lsm<<<8, 256, 0, stream>>>(logits, out);
}